// Round 9
// baseline (54888.849 us; speedup 1.0000x reference)
//
#include <hip/hip_runtime.h>
#include <hip/hip_bf16.h>

#define NB 128   // batch
#define NS 1000  // encoder length
#define NT 256   // decode steps
#define NV 30    // vocab
#define NE 256   // embed dim
#define NKV 256  // key/value dim
#define NH 512   // hidden
#define NG 2048  // 4*NH
#define NK 1024  // GEMM K dim

typedef __hip_bfloat16 bf;
typedef unsigned short ushortT;

__device__ __forceinline__ float sigm(float x){ return 1.f/(1.f+__expf(-x)); }
__device__ __forceinline__ float tanh_fast(float x){ float e=__expf(2.f*x); return 1.f - 2.f/(e+1.f); }
__device__ __forceinline__ float bf2f(ushortT u){ return __uint_as_float(((unsigned)u)<<16); }
__device__ __forceinline__ void bf8_to_f(const ushortT* p, float* o){
  uint4 u = *reinterpret_cast<const uint4*>(p);
  o[0]=__uint_as_float(u.x<<16); o[1]=__uint_as_float(u.x&0xffff0000u);
  o[2]=__uint_as_float(u.y<<16); o[3]=__uint_as_float(u.y&0xffff0000u);
  o[4]=__uint_as_float(u.z<<16); o[5]=__uint_as_float(u.z&0xffff0000u);
  o[6]=__uint_as_float(u.w<<16); o[7]=__uint_as_float(u.w&0xffff0000u);
}
__device__ __forceinline__ float ldDual(const void* p, size_t i, bool bfm){
  return bfm ? bf2f(((const ushortT*)p)[i]) : ((const float*)p)[i];
}

// ---- dtype probe: are the float inputs stored as bf16? ----
// Low 16 bits of each dword: bf16 data -> sane exponent (~99.7%); fp32 data ->
// mantissa noise (~6.6% sane). Count over 1024 dwords, threshold 512.
__global__ void k_probe(const unsigned* __restrict__ x, unsigned* __restrict__ flag){
  __shared__ int cnt;
  if (threadIdx.x==0) cnt = 0;
  __syncthreads();
  int c = 0;
  #pragma unroll
  for (int i=0;i<4;++i){
    unsigned d = x[(size_t)threadIdx.x*4 + i];
    unsigned e = (d >> 7) & 0xffu;       // exponent field of low-half bf16
    c += (e >= 119 && e <= 135) ? 1 : 0; // |x| in [2^-8, 2^8]
  }
  atomicAdd(&cnt, c);
  __syncthreads();
  if (threadIdx.x==0) *flag = (cnt >= 512) ? 1u : 0u;
}

// ---- prep: permuted transposed weights (fp32) ----
// Wtp[k][pc], pc = (j<<2)|g  <->  original col = g*512+j; k<512 from W_ih else W_hh.
__global__ void k_wtp(const void* __restrict__ A, const void* __restrict__ Bm,
                      float* __restrict__ Wtp, const unsigned* __restrict__ flag){
  const bool bfm = (*flag != 0);
  int idx = blockIdx.x*256 + threadIdx.x;       // over NK*NG
  int k = idx >> 11, pc = idx & (NG-1);
  int j = pc >> 2, g = pc & 3;
  int col = g*NH + j;
  const void* p = (k < NH) ? A : Bm;
  Wtp[idx] = ldDual(p, (size_t)col*NH + (k & (NH-1)), bfm);
}

// ---- prep: permuted bias sums, both layers ----
__global__ void k_biasp(const void* bi1, const void* bh1, const void* bi2, const void* bh2,
                        float* __restrict__ bsum1, float* __restrict__ bsum2,
                        const unsigned* __restrict__ flag){
  const bool bfm = (*flag != 0);
  int idx = blockIdx.x*256 + threadIdx.x;       // over 2*NG
  int which = idx >= NG; int pc = idx & (NG-1);
  int j = pc >> 2, g = pc & 3;
  int col = g*NH + j;
  const void* a = which ? bi2 : bi1;
  const void* c = which ? bh2 : bh1;
  float v = ldDual(a, col, bfm) + ldDual(c, col, bfm);
  (which ? bsum2 : bsum1)[pc] = v;
}

// ---- init: ctx0 = mean_s value[b,s,:]; e0 = emb[y[0,b]]; zero states ----
__global__ void k_init(const void* __restrict__ value, const int* __restrict__ y,
                       const void* __restrict__ emb,
                       float* __restrict__ X1a, float* __restrict__ X2a,
                       float* __restrict__ c1, float* __restrict__ c2,
                       const unsigned* __restrict__ flag){
  const bool bfm = (*flag != 0);
  int b = blockIdx.x, tid = threadIdx.x;
  float acc = 0.f;
  if (bfm){
    const ushortT* vcol = (const ushortT*)value + (size_t)b*NS*NKV + tid;
    for (int s=0;s<NS;++s) acc += bf2f(vcol[(size_t)s*NKV]);
  } else {
    const float* vcol = (const float*)value + (size_t)b*NS*NKV + tid;
    for (int s=0;s<NS;++s) acc += vcol[(size_t)s*NKV];
  }
  X1a[(size_t)b*NK + NE + tid] = acc * (1.f/NS);
  int yv = y[b];
  X1a[(size_t)b*NK + tid] = ldDual(emb, (size_t)yv*NE + tid, bfm);
  X1a[(size_t)b*NK + 512 + tid] = 0.f; X1a[(size_t)b*NK + 768 + tid] = 0.f;
  X2a[(size_t)b*NK + 512 + tid] = 0.f; X2a[(size_t)b*NK + 768 + tid] = 0.f;
  c1[(size_t)b*NH + tid] = 0.f; c1[(size_t)b*NH + 256 + tid] = 0.f;
  c2[(size_t)b*NH + tid] = 0.f; c2[(size_t)b*NH + 256 + tid] = 0.f;
}

// ---- per-step LSTM v3: fp32 GEMM [128 x 2048] = X[128x1024] * Wtp, fused cell ----
// 256 blocks x 512 thr. Tile 32 rows x 32 permuted-cols; K split across 2 halves.
// Grid decode keeps all rb-peers of a col-slice on one XCD (weights L2-resident).
__global__ __launch_bounds__(512) void k_lstm(
    const float* __restrict__ X, const float* __restrict__ Wtp,
    const float* __restrict__ bsump,
    float* __restrict__ cstate,
    float* __restrict__ outC, int outCstride, int hasC,
    float* __restrict__ outH)   // caller pre-offsets outH by +NH; row stride NK
{
  const int i = blockIdx.x;
  const int cb = ((i & 7) << 3) | ((i >> 3) & 7);   // 0..63 col-slice
  const int rb = i >> 6;                            // 0..3 row-slice
  const int r0 = rb * 32;
  const int pc0 = cb * 32;
  const int tid = threadIdx.x;
  const int khalf = tid >> 8;
  const int t8 = tid & 255;
  const int rp = t8 >> 4;              // 0..15 row-pair
  const int cp = t8 & 15;              // 0..15 col-pair
  __shared__ float Xs[2][64][33];
  __shared__ float redbuf[256][4];
  __shared__ float gbuf[32][33];

  float a00=0.f, a01=0.f, a10=0.f, a11=0.f;
  const int kbase = khalf * 512;
  const int sr  = t8 >> 4;             // staging rows sr, sr+16
  const int sk4 = (t8 & 15) * 4;       // staging kk base

  for (int cch = 0; cch < 8; ++cch){
    __syncthreads();
    {
      const float4 v0 = *reinterpret_cast<const float4*>(
          X + (size_t)(r0+sr)*NK + kbase + cch*64 + sk4);
      const float4 v1 = *reinterpret_cast<const float4*>(
          X + (size_t)(r0+sr+16)*NK + kbase + cch*64 + sk4);
      Xs[khalf][sk4+0][sr]    = v0.x; Xs[khalf][sk4+1][sr]    = v0.y;
      Xs[khalf][sk4+2][sr]    = v0.z; Xs[khalf][sk4+3][sr]    = v0.w;
      Xs[khalf][sk4+0][sr+16] = v1.x; Xs[khalf][sk4+1][sr+16] = v1.y;
      Xs[khalf][sk4+2][sr+16] = v1.z; Xs[khalf][sk4+3][sr+16] = v1.w;
    }
    __syncthreads();
    const float* wp = Wtp + (size_t)(kbase + cch*64)*NG + pc0 + cp*2;
    #pragma unroll 8
    for (int kk=0; kk<64; ++kk){
      const float2 w = *reinterpret_cast<const float2*>(wp + (size_t)kk*NG);
      const float2 x = *reinterpret_cast<const float2*>(&Xs[khalf][kk][rp*2]);
      a00 = fmaf(x.x, w.x, a00); a01 = fmaf(x.x, w.y, a01);
      a10 = fmaf(x.y, w.x, a10); a11 = fmaf(x.y, w.y, a11);
    }
  }
  if (khalf == 1){
    redbuf[t8][0]=a00; redbuf[t8][1]=a01; redbuf[t8][2]=a10; redbuf[t8][3]=a11;
  }
  __syncthreads();
  if (khalf == 0){
    a00 += redbuf[t8][0]; a01 += redbuf[t8][1];
    a10 += redbuf[t8][2]; a11 += redbuf[t8][3];
    gbuf[rp*2+0][cp*2+0]=a00; gbuf[rp*2+0][cp*2+1]=a01;
    gbuf[rp*2+1][cp*2+0]=a10; gbuf[rp*2+1][cp*2+1]=a11;
  }
  __syncthreads();
  if (tid < 256){
    const int er = tid >> 3;            // 0..31
    const int jj = tid & 7;             // 0..7
    const int r = r0 + er;
    const int jg = cb*8 + jj;           // global j in [0,512)
    const int pb = pc0 + jj*4;
    float iv = gbuf[er][jj*4+0] + bsump[pb+0];
    float fv = gbuf[er][jj*4+1] + bsump[pb+1];
    float gv = gbuf[er][jj*4+2] + bsump[pb+2];
    float ov = gbuf[er][jj*4+3] + bsump[pb+3];
    float cold = cstate[(size_t)r*NH + jg];
    float cn = sigm(fv)*cold + sigm(iv)*tanh_fast(gv);
    float hn = sigm(ov)*tanh_fast(cn);
    cstate[(size_t)r*NH + jg] = cn;
    if (hasC) outC[(size_t)r*outCstride + jg] = cn;
    outH[(size_t)r*NK + jg] = hn;
  }
}

// ---- per-step attention (fp32 core; dual-dtype reads; vectorized V/ctx) ----
__global__ __launch_bounds__(256) void k_attn(
    const float* __restrict__ c2, const void* __restrict__ Wq, const void* __restrict__ bq,
    const void* __restrict__ key, const void* __restrict__ val,
    const void* __restrict__ Wc, const void* __restrict__ bc,
    const int* __restrict__ y, const void* __restrict__ emb,
    float* __restrict__ X1next, void* __restrict__ outp,
    const unsigned* __restrict__ flag, int t)
{
  const bool bfm = (*flag != 0);
  const int b = blockIdx.x, tid = threadIdx.x, lane = tid & 63, wave = tid >> 6;
  __shared__ float c2s[NH];
  __shared__ float qs[NKV];
  __shared__ float ps[NS];
  __shared__ float ctxs[NKV];
  __shared__ float red[8];
  __shared__ float psum[NV][9];
  __shared__ float ctxpart[4][NKV];

  c2s[tid]       = c2[(size_t)b*NH + tid];
  c2s[256 + tid] = c2[(size_t)b*NH + 256 + tid];
  __syncthreads();

  // q[c] = bq[c] + sum_j c2[j] * Wq[c][j]
  {
    float qacc = ldDual(bq, tid, bfm);
    if (bfm){
      const ushortT* wrow = (const ushortT*)Wq + (size_t)tid*NH;
      #pragma unroll 4
      for (int j=0;j<NH;j+=8){
        float wv[8]; bf8_to_f(wrow + j, wv);
        #pragma unroll
        for (int u=0;u<8;++u) qacc = fmaf(wv[u], c2s[j+u], qacc);
      }
    } else {
      const float4* wrow = reinterpret_cast<const float4*>((const float*)Wq + (size_t)tid*NH);
      #pragma unroll 4
      for (int j4=0; j4<NH/4; ++j4){
        float4 w = wrow[j4]; int j = j4*4;
        qacc = fmaf(w.x, c2s[j+0], qacc); qacc = fmaf(w.y, c2s[j+1], qacc);
        qacc = fmaf(w.z, c2s[j+2], qacc); qacc = fmaf(w.w, c2s[j+3], qacc);
      }
    }
    qs[tid] = qacc;
  }
  __syncthreads();

  // energy
  const int k0 = (lane & 15)*16;
  float qreg[16];
  #pragma unroll
  for (int u=0;u<16;++u) qreg[u] = qs[k0+u];
  const float rscale = 0.031622776601683794f; // 1/sqrt(1000)
  for (int s0 = wave*4; s0 < NS; s0 += 16){
    int s = s0 + (lane >> 4);
    float acc = 0.f;
    if (s < NS){
      if (bfm){
        const ushortT* kp = (const ushortT*)key + ((size_t)b*NS + s)*NKV + k0;
        float xv[8];
        bf8_to_f(kp, xv);
        #pragma unroll
        for (int u=0;u<8;++u) acc = fmaf(xv[u], qreg[u], acc);
        bf8_to_f(kp + 8, xv);
        #pragma unroll
        for (int u=0;u<8;++u) acc = fmaf(xv[u], qreg[8+u], acc);
      } else {
        const float* kp = (const float*)key + ((size_t)b*NS + s)*NKV + k0;
        #pragma unroll
        for (int u=0;u<16;++u) acc = fmaf(kp[u], qreg[u], acc);
      }
    }
    acc += __shfl_xor(acc,1); acc += __shfl_xor(acc,2);
    acc += __shfl_xor(acc,4); acc += __shfl_xor(acc,8);
    if ((lane & 15) == 0 && s < NS) ps[s] = (acc + 1e-9f)*rscale;
  }
  __syncthreads();

  // softmax
  float m = -1e30f;
  for (int s=tid; s<NS; s+=256) m = fmaxf(m, ps[s]);
  #pragma unroll
  for (int d=1; d<64; d<<=1) m = fmaxf(m, __shfl_xor(m, d));
  if (lane == 0) red[wave] = m;
  __syncthreads();
  m = fmaxf(fmaxf(red[0],red[1]), fmaxf(red[2],red[3]));
  float sum = 0.f;
  for (int s=tid; s<NS; s+=256){ float p = __expf(ps[s]-m); ps[s] = p; sum += p; }
  #pragma unroll
  for (int d=1; d<64; d<<=1) sum += __shfl_xor(sum, d);
  if (lane == 0) red[4+wave] = sum;
  __syncthreads();
  sum = red[4]+red[5]+red[6]+red[7];
  const float invS = 1.f/sum;

  const size_t ATTN_OFF = (size_t)NB*NT*NV;
  if (b == 0){
    for (int s=tid; s<NS; s+=256){
      float v = ps[s]*invS;
      if (bfm) ((bf*)outp)[ATTN_OFF + (size_t)t*NS + s] = __float2bfloat16(v);
      else     ((float*)outp)[ATTN_OFF + (size_t)t*NS + s] = v;
    }
  }

  // ctx: vectorized V reads. lane covers 8 cols; 8 s-streams across block.
  {
    float cacc[8] = {0.f,0.f,0.f,0.f,0.f,0.f,0.f,0.f};
    const int sset = lane >> 5;
    const int kc = (lane & 31) * 8;
    if (bfm){
      const ushortT* vbase = (const ushortT*)val + (size_t)b*NS*NKV + kc;
      for (int s = wave*2 + sset; s < NS; s += 8){
        float p = ps[s];
        float xv[8]; bf8_to_f(vbase + (size_t)s*NKV, xv);
        #pragma unroll
        for (int u=0;u<8;++u) cacc[u] = fmaf(xv[u], p, cacc[u]);
      }
    } else {
      const float* vbase = (const float*)val + (size_t)b*NS*NKV + kc;
      for (int s = wave*2 + sset; s < NS; s += 8){
        float p = ps[s];
        const float4 v0 = *reinterpret_cast<const float4*>(vbase + (size_t)s*NKV);
        const float4 v1 = *reinterpret_cast<const float4*>(vbase + (size_t)s*NKV + 4);
        cacc[0]=fmaf(v0.x,p,cacc[0]); cacc[1]=fmaf(v0.y,p,cacc[1]);
        cacc[2]=fmaf(v0.z,p,cacc[2]); cacc[3]=fmaf(v0.w,p,cacc[3]);
        cacc[4]=fmaf(v1.x,p,cacc[4]); cacc[5]=fmaf(v1.y,p,cacc[5]);
        cacc[6]=fmaf(v1.z,p,cacc[6]); cacc[7]=fmaf(v1.w,p,cacc[7]);
      }
    }
    #pragma unroll
    for (int u=0;u<8;++u) cacc[u] += __shfl_xor(cacc[u], 32);
    if (lane < 32){
      #pragma unroll
      for (int u=0;u<8;++u) ctxpart[wave][kc+u] = cacc[u];
    }
  }
  __syncthreads();
  float ctxv = (ctxpart[0][tid]+ctxpart[1][tid]+ctxpart[2][tid]+ctxpart[3][tid]) * invS;
  ctxs[tid] = ctxv;
  X1next[(size_t)b*NK + NE + tid] = ctxv;
  __syncthreads();

  // pred[v] = bc[v] + sum_k [ctx||q][k] * Wc[v][k]
  {
    int vIdx = tid >> 3, part = tid & 7;
    if (vIdx < NV){
      float a = 0.f;
      int kb0 = part*64;
      for (int k=kb0; k<kb0+64; ++k){
        float xv = (k < NKV) ? ctxs[k] : qs[k-NKV];
        a = fmaf(xv, ldDual(Wc, (size_t)vIdx*(2*NKV) + k, bfm), a);
      }
      psum[vIdx][part] = a;
    }
  }
  __syncthreads();
  if (tid < NV){
    float a = ldDual(bc, tid, bfm);
    #pragma unroll
    for (int p=0;p<8;++p) a += psum[tid][p];
    size_t oi = (size_t)b*(NT*NV) + (size_t)t*NV + tid;
    if (bfm) ((bf*)outp)[oi] = __float2bfloat16(a);
    else     ((float*)outp)[oi] = a;
  }

  // stage next step's embedding row into X1next[:, 0:NE)
  if (t + 1 < NT){
    int yv = y[(size_t)(t+1)*NB + b];
    X1next[(size_t)b*NK + tid] = ldDual(emb, (size_t)yv*NE + tid, bfm);
  }
}

extern "C" void kernel_launch(void* const* d_in, const int* in_sizes, int n_in,
                              void* d_out, int out_size, void* d_ws, size_t ws_size,
                              hipStream_t stream)
{
  const void* enc_key = d_in[0];
  const void* value   = d_in[1];
  const int*  y       = (const int*)d_in[2];
  // d_in[3] = encoder_len, unused (reference discards the mask)
  const void* emb     = d_in[4];
  const void* W_ih1   = d_in[5];
  const void* b_ih1   = d_in[6];
  const void* W_hh1   = d_in[7];
  const void* b_hh1   = d_in[8];
  const void* W_ih2   = d_in[9];
  const void* b_ih2   = d_in[10];
  const void* W_hh2   = d_in[11];
  const void* b_hh2   = d_in[12];
  const void* Wq      = d_in[13];
  const void* bq      = d_in[14];
  const void* Wc      = d_in[15];
  const void* bc      = d_in[16];

  char* base = (char*)d_ws; size_t off = 0;
  auto alloc = [&](size_t bytes)->char*{
    char* p = base + off; off += (bytes + 255) & ~(size_t)255; return p;
  };
  float* Wtp1 = (float*)alloc((size_t)NK*NG*4);   // 8 MB
  float* Wtp2 = (float*)alloc((size_t)NK*NG*4);   // 8 MB
  float* bsum1 = (float*)alloc((size_t)NG*4);
  float* bsum2 = (float*)alloc((size_t)NG*4);
  float* X1[2] = {(float*)alloc((size_t)NB*NK*4), (float*)alloc((size_t)NB*NK*4)};
  float* X2[2] = {(float*)alloc((size_t)NB*NK*4), (float*)alloc((size_t)NB*NK*4)};
  float* c1 = (float*)alloc((size_t)NB*NH*4);
  float* c2 = (float*)alloc((size_t)NB*NH*4);
  unsigned* flag = (unsigned*)alloc(256);
  (void)ws_size;

  k_probe<<<1, 256, 0, stream>>>((const unsigned*)enc_key, flag);
  k_wtp<<<(NK*NG)/256, 256, 0, stream>>>(W_ih1, W_hh1, Wtp1, flag);
  k_wtp<<<(NK*NG)/256, 256, 0, stream>>>(W_ih2, W_hh2, Wtp2, flag);
  k_biasp<<<(2*NG)/256, 256, 0, stream>>>(b_ih1, b_hh1, b_ih2, b_hh2, bsum1, bsum2, flag);
  k_init<<<NB, 256, 0, stream>>>(value, y, emb, X1[0], X2[0], c1, c2, flag);

  for (int t=0; t<NT; ++t){
    int cur = t & 1, nxt = cur ^ 1;
    // LSTM1: X1[cur] -> (c1, h1);  c1n -> X2[cur][:,0:512), h1n -> X1[nxt][:,512:1024)
    k_lstm<<<256, 512, 0, stream>>>(X1[cur], Wtp1, bsum1, c1,
                                    X2[cur], NK, 1, X1[nxt] + NH);
    // LSTM2: X2[cur] -> (c2, h2);  h2n -> X2[nxt][:,512:1024); attn reads c2
    k_lstm<<<256, 512, 0, stream>>>(X2[cur], Wtp2, bsum2, c2,
                                    nullptr, 0, 0, X2[nxt] + NH);
    if (true)
      k_attn<<<NB, 256, 0, stream>>>(c2, Wq, bq, enc_key, value, Wc, bc,
                                     y, emb, X1[nxt], d_out, flag, t);
  }
}

// Round 10
// 43249.500 us; speedup vs baseline: 1.2691x; 1.2691x over previous
//
#include <hip/hip_runtime.h>
#include <hip/hip_bf16.h>

#define NB 128   // batch
#define NS 1000  // encoder length
#define NT 256   // decode steps
#define NV 30    // vocab
#define NE 256   // embed dim
#define NKV 256  // key/value dim
#define NH 512   // hidden
#define NG 2048  // 4*NH
#define NK 1024  // GEMM K dim

typedef __hip_bfloat16 bf;
typedef unsigned short ushortT;

__device__ __forceinline__ float sigm(float x){ return 1.f/(1.f+__expf(-x)); }
__device__ __forceinline__ float tanh_fast(float x){ float e=__expf(2.f*x); return 1.f - 2.f/(e+1.f); }
__device__ __forceinline__ float bf2f(ushortT u){ return __uint_as_float(((unsigned)u)<<16); }
__device__ __forceinline__ void bf8_to_f(const ushortT* p, float* o){
  uint4 u = *reinterpret_cast<const uint4*>(p);
  o[0]=__uint_as_float(u.x<<16); o[1]=__uint_as_float(u.x&0xffff0000u);
  o[2]=__uint_as_float(u.y<<16); o[3]=__uint_as_float(u.y&0xffff0000u);
  o[4]=__uint_as_float(u.z<<16); o[5]=__uint_as_float(u.z&0xffff0000u);
  o[6]=__uint_as_float(u.w<<16); o[7]=__uint_as_float(u.w&0xffff0000u);
}
__device__ __forceinline__ float ldDual(const void* p, size_t i, bool bfm){
  return bfm ? bf2f(((const ushortT*)p)[i]) : ((const float*)p)[i];
}

// ---- dtype probe: are the float inputs stored as bf16? ----
__global__ void k_probe(const unsigned* __restrict__ x, unsigned* __restrict__ flag){
  __shared__ int cnt;
  if (threadIdx.x==0) cnt = 0;
  __syncthreads();
  int c = 0;
  #pragma unroll
  for (int i=0;i<4;++i){
    unsigned d = x[(size_t)threadIdx.x*4 + i];
    unsigned e = (d >> 7) & 0xffu;       // exponent field of low-half bf16
    c += (e >= 119 && e <= 135) ? 1 : 0; // |x| in [2^-8, 2^8]
  }
  atomicAdd(&cnt, c);
  __syncthreads();
  if (threadIdx.x==0) *flag = (cnt >= 512) ? 1u : 0u;
}

// ---- prep: permuted transposed weights (fp32) ----
__global__ void k_wtp(const void* __restrict__ A, const void* __restrict__ Bm,
                      float* __restrict__ Wtp, const unsigned* __restrict__ flag){
  const bool bfm = (*flag != 0);
  int idx = blockIdx.x*256 + threadIdx.x;       // over NK*NG
  int k = idx >> 11, pc = idx & (NG-1);
  int j = pc >> 2, g = pc & 3;
  int col = g*NH + j;
  const void* p = (k < NH) ? A : Bm;
  Wtp[idx] = ldDual(p, (size_t)col*NH + (k & (NH-1)), bfm);
}

// ---- prep: permuted bias sums, both layers ----
__global__ void k_biasp(const void* bi1, const void* bh1, const void* bi2, const void* bh2,
                        float* __restrict__ bsum1, float* __restrict__ bsum2,
                        const unsigned* __restrict__ flag){
  const bool bfm = (*flag != 0);
  int idx = blockIdx.x*256 + threadIdx.x;       // over 2*NG
  int which = idx >= NG; int pc = idx & (NG-1);
  int j = pc >> 2, g = pc & 3;
  int col = g*NH + j;
  const void* a = which ? bi2 : bi1;
  const void* c = which ? bh2 : bh1;
  float v = ldDual(a, col, bfm) + ldDual(c, col, bfm);
  (which ? bsum2 : bsum1)[pc] = v;
}

// ---- init: ctx0 = mean_s value[b,s,:]; e0 = emb[y[0,b]]; zero states ----
__global__ void k_init(const void* __restrict__ value, const int* __restrict__ y,
                       const void* __restrict__ emb,
                       float* __restrict__ X1a, float* __restrict__ X2a,
                       float* __restrict__ c1, float* __restrict__ c2,
                       const unsigned* __restrict__ flag){
  const bool bfm = (*flag != 0);
  int b = blockIdx.x, tid = threadIdx.x;
  float acc = 0.f;
  if (bfm){
    const ushortT* vcol = (const ushortT*)value + (size_t)b*NS*NKV + tid;
    for (int s=0;s<NS;++s) acc += bf2f(vcol[(size_t)s*NKV]);
  } else {
    const float* vcol = (const float*)value + (size_t)b*NS*NKV + tid;
    for (int s=0;s<NS;++s) acc += vcol[(size_t)s*NKV];
  }
  X1a[(size_t)b*NK + NE + tid] = acc * (1.f/NS);
  int yv = y[b];
  X1a[(size_t)b*NK + tid] = ldDual(emb, (size_t)yv*NE + tid, bfm);
  X1a[(size_t)b*NK + 512 + tid] = 0.f; X1a[(size_t)b*NK + 768 + tid] = 0.f;
  X2a[(size_t)b*NK + 512 + tid] = 0.f; X2a[(size_t)b*NK + 768 + tid] = 0.f;
  c1[(size_t)b*NH + tid] = 0.f; c1[(size_t)b*NH + 256 + tid] = 0.f;
  c2[(size_t)b*NH + tid] = 0.f; c2[(size_t)b*NH + 256 + tid] = 0.f;
}

// ---- per-step LSTM (validated): fp32 GEMM [128 x 2048] = X[128x1024] * Wtp, fused cell ----
__global__ __launch_bounds__(512) void k_lstm(
    const float* __restrict__ X, const float* __restrict__ Wtp,
    const float* __restrict__ bsump,
    float* __restrict__ cstate,
    float* __restrict__ outC, int outCstride, int hasC,
    float* __restrict__ outH)   // caller pre-offsets outH by +NH; row stride NK
{
  const int i = blockIdx.x;
  const int cb = ((i & 7) << 3) | ((i >> 3) & 7);   // 0..63 col-slice
  const int rb = i >> 6;                            // 0..3 row-slice
  const int r0 = rb * 32;
  const int pc0 = cb * 32;
  const int tid = threadIdx.x;
  const int khalf = tid >> 8;
  const int t8 = tid & 255;
  const int rp = t8 >> 4;              // 0..15 row-pair
  const int cp = t8 & 15;              // 0..15 col-pair
  __shared__ float Xs[2][64][33];
  __shared__ float redbuf[256][4];
  __shared__ float gbuf[32][33];

  float a00=0.f, a01=0.f, a10=0.f, a11=0.f;
  const int kbase = khalf * 512;
  const int sr  = t8 >> 4;             // staging rows sr, sr+16
  const int sk4 = (t8 & 15) * 4;       // staging kk base

  for (int cch = 0; cch < 8; ++cch){
    __syncthreads();
    {
      const float4 v0 = *reinterpret_cast<const float4*>(
          X + (size_t)(r0+sr)*NK + kbase + cch*64 + sk4);
      const float4 v1 = *reinterpret_cast<const float4*>(
          X + (size_t)(r0+sr+16)*NK + kbase + cch*64 + sk4);
      Xs[khalf][sk4+0][sr]    = v0.x; Xs[khalf][sk4+1][sr]    = v0.y;
      Xs[khalf][sk4+2][sr]    = v0.z; Xs[khalf][sk4+3][sr]    = v0.w;
      Xs[khalf][sk4+0][sr+16] = v1.x; Xs[khalf][sk4+1][sr+16] = v1.y;
      Xs[khalf][sk4+2][sr+16] = v1.z; Xs[khalf][sk4+3][sr+16] = v1.w;
    }
    __syncthreads();
    const float* wp = Wtp + (size_t)(kbase + cch*64)*NG + pc0 + cp*2;
    #pragma unroll 8
    for (int kk=0; kk<64; ++kk){
      const float2 w = *reinterpret_cast<const float2*>(wp + (size_t)kk*NG);
      const float2 x = *reinterpret_cast<const float2*>(&Xs[khalf][kk][rp*2]);
      a00 = fmaf(x.x, w.x, a00); a01 = fmaf(x.x, w.y, a01);
      a10 = fmaf(x.y, w.x, a10); a11 = fmaf(x.y, w.y, a11);
    }
  }
  if (khalf == 1){
    redbuf[t8][0]=a00; redbuf[t8][1]=a01; redbuf[t8][2]=a10; redbuf[t8][3]=a11;
  }
  __syncthreads();
  if (khalf == 0){
    a00 += redbuf[t8][0]; a01 += redbuf[t8][1];
    a10 += redbuf[t8][2]; a11 += redbuf[t8][3];
    gbuf[rp*2+0][cp*2+0]=a00; gbuf[rp*2+0][cp*2+1]=a01;
    gbuf[rp*2+1][cp*2+0]=a10; gbuf[rp*2+1][cp*2+1]=a11;
  }
  __syncthreads();
  if (tid < 256){
    const int er = tid >> 3;            // 0..31
    const int jj = tid & 7;             // 0..7
    const int r = r0 + er;
    const int jg = cb*8 + jj;           // global j in [0,512)
    const int pb = pc0 + jj*4;
    float iv = gbuf[er][jj*4+0] + bsump[pb+0];
    float fv = gbuf[er][jj*4+1] + bsump[pb+1];
    float gv = gbuf[er][jj*4+2] + bsump[pb+2];
    float ov = gbuf[er][jj*4+3] + bsump[pb+3];
    float cold = cstate[(size_t)r*NH + jg];
    float cn = sigm(fv)*cold + sigm(iv)*tanh_fast(gv);
    float hn = sigm(ov)*tanh_fast(cn);
    cstate[(size_t)r*NH + jg] = cn;
    if (hasC) outC[(size_t)r*outCstride + jg] = cn;
    outH[(size_t)r*NK + jg] = hn;
  }
}

// ---- per-step attention: R4-validated algorithm widened to 512 thr (8 waves) ----
__global__ __launch_bounds__(512) void k_attn(
    const float* __restrict__ c2, const void* __restrict__ Wq, const void* __restrict__ bq,
    const void* __restrict__ key, const void* __restrict__ val,
    const void* __restrict__ Wc, const void* __restrict__ bc,
    const int* __restrict__ y, const void* __restrict__ emb,
    float* __restrict__ X1next, void* __restrict__ outp,
    const unsigned* __restrict__ flag, int t)
{
  const bool bfm = (*flag != 0);
  const int b = blockIdx.x, tid = threadIdx.x, lane = tid & 63, wave = tid >> 6;
  __shared__ float c2s[NH];
  __shared__ float qs[NKV];
  __shared__ float ps[NS];
  __shared__ float ctxs[NKV];
  __shared__ float red[16];
  __shared__ float psum[NV][17];
  __shared__ float ctxpart[8][NKV];

  c2s[tid] = c2[(size_t)b*NH + tid];
  __syncthreads();

  // q[c] = bq[c] + sum_j c2[j] * Wq[c][j]   (threads 0..255)
  if (tid < NKV){
    float qacc = ldDual(bq, tid, bfm);
    if (bfm){
      const ushortT* wrow = (const ushortT*)Wq + (size_t)tid*NH;
      #pragma unroll 4
      for (int j=0;j<NH;j+=8){
        float wv[8]; bf8_to_f(wrow + j, wv);
        #pragma unroll
        for (int u=0;u<8;++u) qacc = fmaf(wv[u], c2s[j+u], qacc);
      }
    } else {
      const float4* wrow = reinterpret_cast<const float4*>((const float*)Wq + (size_t)tid*NH);
      #pragma unroll 4
      for (int j4=0; j4<NH/4; ++j4){
        float4 w = wrow[j4]; int j = j4*4;
        qacc = fmaf(w.x, c2s[j+0], qacc); qacc = fmaf(w.y, c2s[j+1], qacc);
        qacc = fmaf(w.z, c2s[j+2], qacc); qacc = fmaf(w.w, c2s[j+3], qacc);
      }
    }
    qs[tid] = qacc;
  }
  __syncthreads();

  // energy: 16 lanes per s, 4 s per wave per pass, 8 waves -> 32 s/pass
  const int k0 = (lane & 15)*16;
  float qreg[16];
  #pragma unroll
  for (int u=0;u<16;++u) qreg[u] = qs[k0+u];
  const float rscale = 0.031622776601683794f; // 1/sqrt(1000)
  for (int s0 = wave*4; s0 < NS; s0 += 32){
    int s = s0 + (lane >> 4);
    float acc = 0.f;
    if (s < NS){
      if (bfm){
        const ushortT* kp = (const ushortT*)key + ((size_t)b*NS + s)*NKV + k0;
        float xv[8];
        bf8_to_f(kp, xv);
        #pragma unroll
        for (int u=0;u<8;++u) acc = fmaf(xv[u], qreg[u], acc);
        bf8_to_f(kp + 8, xv);
        #pragma unroll
        for (int u=0;u<8;++u) acc = fmaf(xv[u], qreg[8+u], acc);
      } else {
        const float* kp = (const float*)key + ((size_t)b*NS + s)*NKV + k0;
        #pragma unroll
        for (int u=0;u<16;++u) acc = fmaf(kp[u], qreg[u], acc);
      }
    }
    acc += __shfl_xor(acc,1); acc += __shfl_xor(acc,2);
    acc += __shfl_xor(acc,4); acc += __shfl_xor(acc,8);
    if ((lane & 15) == 0 && s < NS) ps[s] = (acc + 1e-9f)*rscale;
  }
  __syncthreads();

  // softmax over ps[0..NS), 8-wave reduce
  float m = -1e30f;
  for (int s=tid; s<NS; s+=512) m = fmaxf(m, ps[s]);
  #pragma unroll
  for (int d=1; d<64; d<<=1) m = fmaxf(m, __shfl_xor(m, d));
  if (lane == 0) red[wave] = m;
  __syncthreads();
  m = red[0];
  #pragma unroll
  for (int w=1; w<8; ++w) m = fmaxf(m, red[w]);
  float sum = 0.f;
  for (int s=tid; s<NS; s+=512){ float p = __expf(ps[s]-m); ps[s] = p; sum += p; }
  #pragma unroll
  for (int d=1; d<64; d<<=1) sum += __shfl_xor(sum, d);
  if (lane == 0) red[8+wave] = sum;
  __syncthreads();
  sum = red[8];
  #pragma unroll
  for (int w=1; w<8; ++w) sum += red[8+w];
  const float invS = 1.f/sum;

  const size_t ATTN_OFF = (size_t)NB*NT*NV;
  if (b == 0){
    for (int s=tid; s<NS; s+=512){
      float v = ps[s]*invS;
      if (bfm) ((bf*)outp)[ATTN_OFF + (size_t)t*NS + s] = __float2bfloat16(v);
      else     ((float*)outp)[ATTN_OFF + (size_t)t*NS + s] = v;
    }
  }

  // ctx: 16 s-streams x (32 lanes x 8 cols)
  {
    float cacc[8] = {0.f,0.f,0.f,0.f,0.f,0.f,0.f,0.f};
    const int sset = lane >> 5;
    const int kc = (lane & 31) * 8;
    const int sst = wave*2 + sset;
    if (bfm){
      const ushortT* vbase = (const ushortT*)val + (size_t)b*NS*NKV + kc;
      for (int s = sst; s < NS; s += 16){
        float p = ps[s];
        float xv[8]; bf8_to_f(vbase + (size_t)s*NKV, xv);
        #pragma unroll
        for (int u=0;u<8;++u) cacc[u] = fmaf(xv[u], p, cacc[u]);
      }
    } else {
      const float* vbase = (const float*)val + (size_t)b*NS*NKV + kc;
      for (int s = sst; s < NS; s += 16){
        float p = ps[s];
        const float4 v0 = *reinterpret_cast<const float4*>(vbase + (size_t)s*NKV);
        const float4 v1 = *reinterpret_cast<const float4*>(vbase + (size_t)s*NKV + 4);
        cacc[0]=fmaf(v0.x,p,cacc[0]); cacc[1]=fmaf(v0.y,p,cacc[1]);
        cacc[2]=fmaf(v0.z,p,cacc[2]); cacc[3]=fmaf(v0.w,p,cacc[3]);
        cacc[4]=fmaf(v1.x,p,cacc[4]); cacc[5]=fmaf(v1.y,p,cacc[5]);
        cacc[6]=fmaf(v1.z,p,cacc[6]); cacc[7]=fmaf(v1.w,p,cacc[7]);
      }
    }
    #pragma unroll
    for (int u=0;u<8;++u) cacc[u] += __shfl_xor(cacc[u], 32);
    if (lane < 32){
      #pragma unroll
      for (int u=0;u<8;++u) ctxpart[wave][kc+u] = cacc[u];
    }
  }
  __syncthreads();
  if (tid < NKV){
    float ctxv = 0.f;
    #pragma unroll
    for (int w=0; w<8; ++w) ctxv += ctxpart[w][tid];
    ctxv *= invS;
    ctxs[tid] = ctxv;
    X1next[(size_t)b*NK + NE + tid] = ctxv;
  }
  __syncthreads();

  // pred[v] = bc[v] + sum_k [ctx||q][k] * Wc[v][k]  (16 parts x 32 k)
  {
    int vIdx = tid >> 4, part = tid & 15;
    if (vIdx < NV){
      float a = 0.f;
      int kb0 = part*32;
      for (int k=kb0; k<kb0+32; ++k){
        float xv = (k < NKV) ? ctxs[k] : qs[k-NKV];
        a = fmaf(xv, ldDual(Wc, (size_t)vIdx*(2*NKV) + k, bfm), a);
      }
      psum[vIdx][part] = a;
    }
  }
  __syncthreads();
  if (tid < NV){
    float a = ldDual(bc, tid, bfm);
    #pragma unroll
    for (int p=0;p<16;++p) a += psum[tid][p];
    size_t oi = (size_t)b*(NT*NV) + (size_t)t*NV + tid;
    if (bfm) ((bf*)outp)[oi] = __float2bfloat16(a);
    else     ((float*)outp)[oi] = a;
  }

  // stage next step's embedding row into X1next[:, 0:NE)
  if (t + 1 < NT && tid < NE){
    int yv = y[(size_t)(t+1)*NB + b];
    X1next[(size_t)b*NK + tid] = ldDual(emb, (size_t)yv*NE + tid, bfm);
  }
}

extern "C" void kernel_launch(void* const* d_in, const int* in_sizes, int n_in,
                              void* d_out, int out_size, void* d_ws, size_t ws_size,
                              hipStream_t stream)
{
  const void* enc_key = d_in[0];
  const void* value   = d_in[1];
  const int*  y       = (const int*)d_in[2];
  // d_in[3] = encoder_len, unused (reference discards the mask)
  const void* emb     = d_in[4];
  const void* W_ih1   = d_in[5];
  const void* b_ih1   = d_in[6];
  const void* W_hh1   = d_in[7];
  const void* b_hh1   = d_in[8];
  const void* W_ih2   = d_in[9];
  const void* b_ih2   = d_in[10];
  const void* W_hh2   = d_in[11];
  const void* b_hh2   = d_in[12];
  const void* Wq      = d_in[13];
  const void* bq      = d_in[14];
  const void* Wc      = d_in[15];
  const void* bc      = d_in[16];

  char* base = (char*)d_ws; size_t off = 0;
  auto alloc = [&](size_t bytes)->char*{
    char* p = base + off; off += (bytes + 255) & ~(size_t)255; return p;
  };
  float* Wtp1 = (float*)alloc((size_t)NK*NG*4);   // 8 MB
  float* Wtp2 = (float*)alloc((size_t)NK*NG*4);   // 8 MB
  float* bsum1 = (float*)alloc((size_t)NG*4);
  float* bsum2 = (float*)alloc((size_t)NG*4);
  float* X1[2] = {(float*)alloc((size_t)NB*NK*4), (float*)alloc((size_t)NB*NK*4)};
  float* X2[2] = {(float*)alloc((size_t)NB*NK*4), (float*)alloc((size_t)NB*NK*4)};
  float* c1 = (float*)alloc((size_t)NB*NH*4);
  float* c2 = (float*)alloc((size_t)NB*NH*4);
  unsigned* flag = (unsigned*)alloc(256);
  (void)ws_size;

  k_probe<<<1, 256, 0, stream>>>((const unsigned*)enc_key, flag);
  k_wtp<<<(NK*NG)/256, 256, 0, stream>>>(W_ih1, W_hh1, Wtp1, flag);
  k_wtp<<<(NK*NG)/256, 256, 0, stream>>>(W_ih2, W_hh2, Wtp2, flag);
  k_biasp<<<(2*NG)/256, 256, 0, stream>>>(b_ih1, b_hh1, b_ih2, b_hh2, bsum1, bsum2, flag);
  k_init<<<NB, 256, 0, stream>>>(value, y, emb, X1[0], X2[0], c1, c2, flag);

  for (int t=0; t<NT; ++t){
    int cur = t & 1, nxt = cur ^ 1;
    // LSTM1: X1[cur] -> (c1, h1);  c1n -> X2[cur][:,0:512), h1n -> X1[nxt][:,512:1024)
    k_lstm<<<256, 512, 0, stream>>>(X1[cur], Wtp1, bsum1, c1,
                                    X2[cur], NK, 1, X1[nxt] + NH);
    // LSTM2: X2[cur] -> (c2, h2);  h2n -> X2[nxt][:,512:1024); attn reads c2
    k_lstm<<<256, 512, 0, stream>>>(X2[cur], Wtp2, bsum2, c2,
                                    nullptr, 0, 0, X2[nxt] + NH);
    // attention + pred + next-step staging (512 threads)
    k_attn<<<NB, 512, 0, stream>>>(c2, Wq, bq, enc_key, value, Wc, bc,
                                   y, emb, X1[nxt], d_out, flag, t);
  }
}

// Round 11
// 40937.408 us; speedup vs baseline: 1.3408x; 1.0565x over previous
//
#include <hip/hip_runtime.h>
#include <hip/hip_bf16.h>

#define NB 128   // batch
#define NS 1000  // encoder length
#define NT 256   // decode steps
#define NV 30    // vocab
#define NE 256   // embed dim
#define NKV 256  // key/value dim
#define NH 512   // hidden
#define NG 2048  // 4*NH
#define NK 1024  // GEMM K dim

typedef __hip_bfloat16 bf;
typedef unsigned short ushortT;

__device__ __forceinline__ float sigm(float x){ return 1.f/(1.f+__expf(-x)); }
__device__ __forceinline__ float tanh_fast(float x){ float e=__expf(2.f*x); return 1.f - 2.f/(e+1.f); }
__device__ __forceinline__ float bf2f(ushortT u){ return __uint_as_float(((unsigned)u)<<16); }
__device__ __forceinline__ void bf8_to_f(const ushortT* p, float* o){
  uint4 u = *reinterpret_cast<const uint4*>(p);
  o[0]=__uint_as_float(u.x<<16); o[1]=__uint_as_float(u.x&0xffff0000u);
  o[2]=__uint_as_float(u.y<<16); o[3]=__uint_as_float(u.y&0xffff0000u);
  o[4]=__uint_as_float(u.z<<16); o[5]=__uint_as_float(u.z&0xffff0000u);
  o[6]=__uint_as_float(u.w<<16); o[7]=__uint_as_float(u.w&0xffff0000u);
}
__device__ __forceinline__ float ldDual(const void* p, size_t i, bool bfm){
  return bfm ? bf2f(((const ushortT*)p)[i]) : ((const float*)p)[i];
}

// ---- dtype probe: are the float inputs stored as bf16? ----
__global__ void k_probe(const unsigned* __restrict__ x, unsigned* __restrict__ flag){
  __shared__ int cnt;
  if (threadIdx.x==0) cnt = 0;
  __syncthreads();
  int c = 0;
  #pragma unroll
  for (int i=0;i<4;++i){
    unsigned d = x[(size_t)threadIdx.x*4 + i];
    unsigned e = (d >> 7) & 0xffu;       // exponent field of low-half bf16
    c += (e >= 119 && e <= 135) ? 1 : 0; // |x| in [2^-8, 2^8]
  }
  atomicAdd(&cnt, c);
  __syncthreads();
  if (threadIdx.x==0) *flag = (cnt >= 512) ? 1u : 0u;
}

// ---- prep: permuted transposed weights (fp32) ----
__global__ void k_wtp(const void* __restrict__ A, const void* __restrict__ Bm,
                      float* __restrict__ Wtp, const unsigned* __restrict__ flag){
  const bool bfm = (*flag != 0);
  int idx = blockIdx.x*256 + threadIdx.x;       // over NK*NG
  int k = idx >> 11, pc = idx & (NG-1);
  int j = pc >> 2, g = pc & 3;
  int col = g*NH + j;
  const void* p = (k < NH) ? A : Bm;
  Wtp[idx] = ldDual(p, (size_t)col*NH + (k & (NH-1)), bfm);
}

// ---- prep: permuted bias sums, both layers ----
__global__ void k_biasp(const void* bi1, const void* bh1, const void* bi2, const void* bh2,
                        float* __restrict__ bsum1, float* __restrict__ bsum2,
                        const unsigned* __restrict__ flag){
  const bool bfm = (*flag != 0);
  int idx = blockIdx.x*256 + threadIdx.x;       // over 2*NG
  int which = idx >= NG; int pc = idx & (NG-1);
  int j = pc >> 2, g = pc & 3;
  int col = g*NH + j;
  const void* a = which ? bi2 : bi1;
  const void* c = which ? bh2 : bh1;
  float v = ldDual(a, col, bfm) + ldDual(c, col, bfm);
  (which ? bsum2 : bsum1)[pc] = v;
}

// ---- init: ctx0 = mean_s value[b,s,:]; e0 = emb[y[0,b]]; zero states ----
__global__ void k_init(const void* __restrict__ value, const int* __restrict__ y,
                       const void* __restrict__ emb,
                       float* __restrict__ X1a, float* __restrict__ X2a,
                       float* __restrict__ c1, float* __restrict__ c2,
                       const unsigned* __restrict__ flag){
  const bool bfm = (*flag != 0);
  int b = blockIdx.x, tid = threadIdx.x;
  float acc = 0.f;
  if (bfm){
    const ushortT* vcol = (const ushortT*)value + (size_t)b*NS*NKV + tid;
    for (int s=0;s<NS;++s) acc += bf2f(vcol[(size_t)s*NKV]);
  } else {
    const float* vcol = (const float*)value + (size_t)b*NS*NKV + tid;
    for (int s=0;s<NS;++s) acc += vcol[(size_t)s*NKV];
  }
  X1a[(size_t)b*NK + NE + tid] = acc * (1.f/NS);
  int yv = y[b];
  X1a[(size_t)b*NK + tid] = ldDual(emb, (size_t)yv*NE + tid, bfm);
  X1a[(size_t)b*NK + 512 + tid] = 0.f; X1a[(size_t)b*NK + 768 + tid] = 0.f;
  X2a[(size_t)b*NK + 512 + tid] = 0.f; X2a[(size_t)b*NK + 768 + tid] = 0.f;
  c1[(size_t)b*NH + tid] = 0.f; c1[(size_t)b*NH + 256 + tid] = 0.f;
  c2[(size_t)b*NH + tid] = 0.f; c2[(size_t)b*NH + 256 + tid] = 0.f;
}

// ---- per-step LSTM (validated): fp32 GEMM [128 x 2048] = X[128x1024] * Wtp, fused cell ----
__global__ __launch_bounds__(512) void k_lstm(
    const float* __restrict__ X, const float* __restrict__ Wtp,
    const float* __restrict__ bsump,
    float* __restrict__ cstate,
    float* __restrict__ outC, int outCstride, int hasC,
    float* __restrict__ outH)   // caller pre-offsets outH by +NH; row stride NK
{
  const int i = blockIdx.x;
  const int cb = ((i & 7) << 3) | ((i >> 3) & 7);   // 0..63 col-slice
  const int rb = i >> 6;                            // 0..3 row-slice
  const int r0 = rb * 32;
  const int pc0 = cb * 32;
  const int tid = threadIdx.x;
  const int khalf = tid >> 8;
  const int t8 = tid & 255;
  const int rp = t8 >> 4;              // 0..15 row-pair
  const int cp = t8 & 15;              // 0..15 col-pair
  __shared__ float Xs[2][64][33];
  __shared__ float redbuf[256][4];
  __shared__ float gbuf[32][33];

  float a00=0.f, a01=0.f, a10=0.f, a11=0.f;
  const int kbase = khalf * 512;
  const int sr  = t8 >> 4;             // staging rows sr, sr+16
  const int sk4 = (t8 & 15) * 4;       // staging kk base

  for (int cch = 0; cch < 8; ++cch){
    __syncthreads();
    {
      const float4 v0 = *reinterpret_cast<const float4*>(
          X + (size_t)(r0+sr)*NK + kbase + cch*64 + sk4);
      const float4 v1 = *reinterpret_cast<const float4*>(
          X + (size_t)(r0+sr+16)*NK + kbase + cch*64 + sk4);
      Xs[khalf][sk4+0][sr]    = v0.x; Xs[khalf][sk4+1][sr]    = v0.y;
      Xs[khalf][sk4+2][sr]    = v0.z; Xs[khalf][sk4+3][sr]    = v0.w;
      Xs[khalf][sk4+0][sr+16] = v1.x; Xs[khalf][sk4+1][sr+16] = v1.y;
      Xs[khalf][sk4+2][sr+16] = v1.z; Xs[khalf][sk4+3][sr+16] = v1.w;
    }
    __syncthreads();
    const float* wp = Wtp + (size_t)(kbase + cch*64)*NG + pc0 + cp*2;
    #pragma unroll 8
    for (int kk=0; kk<64; ++kk){
      const float2 w = *reinterpret_cast<const float2*>(wp + (size_t)kk*NG);
      const float2 x = *reinterpret_cast<const float2*>(&Xs[khalf][kk][rp*2]);
      a00 = fmaf(x.x, w.x, a00); a01 = fmaf(x.x, w.y, a01);
      a10 = fmaf(x.y, w.x, a10); a11 = fmaf(x.y, w.y, a11);
    }
  }
  if (khalf == 1){
    redbuf[t8][0]=a00; redbuf[t8][1]=a01; redbuf[t8][2]=a10; redbuf[t8][3]=a11;
  }
  __syncthreads();
  if (khalf == 0){
    a00 += redbuf[t8][0]; a01 += redbuf[t8][1];
    a10 += redbuf[t8][2]; a11 += redbuf[t8][3];
    gbuf[rp*2+0][cp*2+0]=a00; gbuf[rp*2+0][cp*2+1]=a01;
    gbuf[rp*2+1][cp*2+0]=a10; gbuf[rp*2+1][cp*2+1]=a11;
  }
  __syncthreads();
  if (tid < 256){
    const int er = tid >> 3;            // 0..31
    const int jj = tid & 7;             // 0..7
    const int r = r0 + er;
    const int jg = cb*8 + jj;           // global j in [0,512)
    const int pb = pc0 + jj*4;
    float iv = gbuf[er][jj*4+0] + bsump[pb+0];
    float fv = gbuf[er][jj*4+1] + bsump[pb+1];
    float gv = gbuf[er][jj*4+2] + bsump[pb+2];
    float ov = gbuf[er][jj*4+3] + bsump[pb+3];
    float cold = cstate[(size_t)r*NH + jg];
    float cn = sigm(fv)*cold + sigm(iv)*tanh_fast(gv);
    float hn = sigm(ov)*tanh_fast(cn);
    cstate[(size_t)r*NH + jg] = cn;
    if (hasC) outC[(size_t)r*outCstride + jg] = cn;
    outH[(size_t)r*NK + jg] = hn;
  }
}

// ---- per-step attention: 512 thr, 2-way s-stream ILP in energy and ctx ----
__global__ __launch_bounds__(512) void k_attn(
    const float* __restrict__ c2, const void* __restrict__ Wq, const void* __restrict__ bq,
    const void* __restrict__ key, const void* __restrict__ val,
    const void* __restrict__ Wc, const void* __restrict__ bc,
    const int* __restrict__ y, const void* __restrict__ emb,
    float* __restrict__ X1next, void* __restrict__ outp,
    const unsigned* __restrict__ flag, int t)
{
  const bool bfm = (*flag != 0);
  const int b = blockIdx.x, tid = threadIdx.x, lane = tid & 63, wave = tid >> 6;
  __shared__ float c2s[NH];
  __shared__ float qs[NKV];
  __shared__ float ps[NS];
  __shared__ float ctxs[NKV];
  __shared__ float red[16];
  __shared__ float psum[NV][17];
  __shared__ float ctxpart[8][NKV];

  c2s[tid] = c2[(size_t)b*NH + tid];
  __syncthreads();

  // q[c] = bq[c] + sum_j c2[j] * Wq[c][j]   (threads 0..255)
  if (tid < NKV){
    float qacc = ldDual(bq, tid, bfm);
    if (bfm){
      const ushortT* wrow = (const ushortT*)Wq + (size_t)tid*NH;
      #pragma unroll 4
      for (int j=0;j<NH;j+=8){
        float wv[8]; bf8_to_f(wrow + j, wv);
        #pragma unroll
        for (int u=0;u<8;++u) qacc = fmaf(wv[u], c2s[j+u], qacc);
      }
    } else {
      const float4* wrow = reinterpret_cast<const float4*>((const float*)Wq + (size_t)tid*NH);
      #pragma unroll 4
      for (int j4=0; j4<NH/4; ++j4){
        float4 w = wrow[j4]; int j = j4*4;
        qacc = fmaf(w.x, c2s[j+0], qacc); qacc = fmaf(w.y, c2s[j+1], qacc);
        qacc = fmaf(w.z, c2s[j+2], qacc); qacc = fmaf(w.w, c2s[j+3], qacc);
      }
    }
    qs[tid] = qacc;
  }
  __syncthreads();

  // energy: 16 lanes per s; 8 s per wave-iter (2 independent streams per lane-group)
  const int k0 = (lane & 15)*16;
  float qreg[16];
  #pragma unroll
  for (int u=0;u<16;++u) qreg[u] = qs[k0+u];
  const float rscale = 0.031622776601683794f; // 1/sqrt(1000)
  for (int s0 = wave*8; s0 < NS; s0 += 64){
    int sA = s0 + (lane >> 4);
    int sB = sA + 4;
    float aA = 0.f, aB = 0.f;
    if (bfm){
      if (sA < NS){
        const ushortT* kp = (const ushortT*)key + ((size_t)b*NS + sA)*NKV + k0;
        float xv[8];
        bf8_to_f(kp, xv);
        #pragma unroll
        for (int u=0;u<8;++u) aA = fmaf(xv[u], qreg[u], aA);
        bf8_to_f(kp + 8, xv);
        #pragma unroll
        for (int u=0;u<8;++u) aA = fmaf(xv[u], qreg[8+u], aA);
      }
      if (sB < NS){
        const ushortT* kp = (const ushortT*)key + ((size_t)b*NS + sB)*NKV + k0;
        float xv[8];
        bf8_to_f(kp, xv);
        #pragma unroll
        for (int u=0;u<8;++u) aB = fmaf(xv[u], qreg[u], aB);
        bf8_to_f(kp + 8, xv);
        #pragma unroll
        for (int u=0;u<8;++u) aB = fmaf(xv[u], qreg[8+u], aB);
      }
    } else {
      const float* kA = (const float*)key + ((size_t)b*NS + sA)*NKV + k0;
      const float* kB = (const float*)key + ((size_t)b*NS + sB)*NKV + k0;
      float4 a0,a1,a2,a3, b0,b1,b2,b3;
      bool gA = (sA < NS), gB = (sB < NS);
      if (gA){
        a0 = *reinterpret_cast<const float4*>(kA);
        a1 = *reinterpret_cast<const float4*>(kA+4);
        a2 = *reinterpret_cast<const float4*>(kA+8);
        a3 = *reinterpret_cast<const float4*>(kA+12);
      }
      if (gB){
        b0 = *reinterpret_cast<const float4*>(kB);
        b1 = *reinterpret_cast<const float4*>(kB+4);
        b2 = *reinterpret_cast<const float4*>(kB+8);
        b3 = *reinterpret_cast<const float4*>(kB+12);
      }
      if (gA){
        aA = fmaf(a0.x,qreg[0],aA); aA = fmaf(a0.y,qreg[1],aA);
        aA = fmaf(a0.z,qreg[2],aA); aA = fmaf(a0.w,qreg[3],aA);
        aA = fmaf(a1.x,qreg[4],aA); aA = fmaf(a1.y,qreg[5],aA);
        aA = fmaf(a1.z,qreg[6],aA); aA = fmaf(a1.w,qreg[7],aA);
        aA = fmaf(a2.x,qreg[8],aA); aA = fmaf(a2.y,qreg[9],aA);
        aA = fmaf(a2.z,qreg[10],aA); aA = fmaf(a2.w,qreg[11],aA);
        aA = fmaf(a3.x,qreg[12],aA); aA = fmaf(a3.y,qreg[13],aA);
        aA = fmaf(a3.z,qreg[14],aA); aA = fmaf(a3.w,qreg[15],aA);
      }
      if (gB){
        aB = fmaf(b0.x,qreg[0],aB); aB = fmaf(b0.y,qreg[1],aB);
        aB = fmaf(b0.z,qreg[2],aB); aB = fmaf(b0.w,qreg[3],aB);
        aB = fmaf(b1.x,qreg[4],aB); aB = fmaf(b1.y,qreg[5],aB);
        aB = fmaf(b1.z,qreg[6],aB); aB = fmaf(b1.w,qreg[7],aB);
        aB = fmaf(b2.x,qreg[8],aB); aB = fmaf(b2.y,qreg[9],aB);
        aB = fmaf(b2.z,qreg[10],aB); aB = fmaf(b2.w,qreg[11],aB);
        aB = fmaf(b3.x,qreg[12],aB); aB = fmaf(b3.y,qreg[13],aB);
        aB = fmaf(b3.z,qreg[14],aB); aB = fmaf(b3.w,qreg[15],aB);
      }
    }
    aA += __shfl_xor(aA,1); aA += __shfl_xor(aA,2);
    aA += __shfl_xor(aA,4); aA += __shfl_xor(aA,8);
    aB += __shfl_xor(aB,1); aB += __shfl_xor(aB,2);
    aB += __shfl_xor(aB,4); aB += __shfl_xor(aB,8);
    if ((lane & 15) == 0){
      if (sA < NS) ps[sA] = (aA + 1e-9f)*rscale;
      if (sB < NS) ps[sB] = (aB + 1e-9f)*rscale;
    }
  }
  __syncthreads();

  // softmax over ps[0..NS), 8-wave reduce
  float m = -1e30f;
  for (int s=tid; s<NS; s+=512) m = fmaxf(m, ps[s]);
  #pragma unroll
  for (int d=1; d<64; d<<=1) m = fmaxf(m, __shfl_xor(m, d));
  if (lane == 0) red[wave] = m;
  __syncthreads();
  m = red[0];
  #pragma unroll
  for (int w=1; w<8; ++w) m = fmaxf(m, red[w]);
  float sum = 0.f;
  for (int s=tid; s<NS; s+=512){ float p = __expf(ps[s]-m); ps[s] = p; sum += p; }
  #pragma unroll
  for (int d=1; d<64; d<<=1) sum += __shfl_xor(sum, d);
  if (lane == 0) red[8+wave] = sum;
  __syncthreads();
  sum = red[8];
  #pragma unroll
  for (int w=1; w<8; ++w) sum += red[8+w];
  const float invS = 1.f/sum;

  const size_t ATTN_OFF = (size_t)NB*NT*NV;
  if (b == 0){
    for (int s=tid; s<NS; s+=512){
      float v = ps[s]*invS;
      if (bfm) ((bf*)outp)[ATTN_OFF + (size_t)t*NS + s] = __float2bfloat16(v);
      else     ((float*)outp)[ATTN_OFF + (size_t)t*NS + s] = v;
    }
  }

  // ctx: 16 s-streams x (32 lanes x 8 cols), 2-way unrolled (s, s+16)
  {
    float ca[8] = {0.f,0.f,0.f,0.f,0.f,0.f,0.f,0.f};
    float cb2[8] = {0.f,0.f,0.f,0.f,0.f,0.f,0.f,0.f};
    const int sset = lane >> 5;
    const int kc = (lane & 31) * 8;
    const int sst = wave*2 + sset;
    int s = sst;
    if (bfm){
      const ushortT* vbase = (const ushortT*)val + (size_t)b*NS*NKV + kc;
      for (; s + 16 < NS; s += 32){
        float p0 = ps[s], p1 = ps[s+16];
        float xv[8];
        bf8_to_f(vbase + (size_t)s*NKV, xv);
        #pragma unroll
        for (int u=0;u<8;++u) ca[u] = fmaf(xv[u], p0, ca[u]);
        bf8_to_f(vbase + (size_t)(s+16)*NKV, xv);
        #pragma unroll
        for (int u=0;u<8;++u) cb2[u] = fmaf(xv[u], p1, cb2[u]);
      }
      if (s < NS){
        float p0 = ps[s];
        float xv[8]; bf8_to_f(vbase + (size_t)s*NKV, xv);
        #pragma unroll
        for (int u=0;u<8;++u) ca[u] = fmaf(xv[u], p0, ca[u]);
      }
    } else {
      const float* vbase = (const float*)val + (size_t)b*NS*NKV + kc;
      for (; s + 16 < NS; s += 32){
        float p0 = ps[s], p1 = ps[s+16];
        const float4 v0 = *reinterpret_cast<const float4*>(vbase + (size_t)s*NKV);
        const float4 v1 = *reinterpret_cast<const float4*>(vbase + (size_t)s*NKV + 4);
        const float4 w0 = *reinterpret_cast<const float4*>(vbase + (size_t)(s+16)*NKV);
        const float4 w1 = *reinterpret_cast<const float4*>(vbase + (size_t)(s+16)*NKV + 4);
        ca[0]=fmaf(v0.x,p0,ca[0]); ca[1]=fmaf(v0.y,p0,ca[1]);
        ca[2]=fmaf(v0.z,p0,ca[2]); ca[3]=fmaf(v0.w,p0,ca[3]);
        ca[4]=fmaf(v1.x,p0,ca[4]); ca[5]=fmaf(v1.y,p0,ca[5]);
        ca[6]=fmaf(v1.z,p0,ca[6]); ca[7]=fmaf(v1.w,p0,ca[7]);
        cb2[0]=fmaf(w0.x,p1,cb2[0]); cb2[1]=fmaf(w0.y,p1,cb2[1]);
        cb2[2]=fmaf(w0.z,p1,cb2[2]); cb2[3]=fmaf(w0.w,p1,cb2[3]);
        cb2[4]=fmaf(w1.x,p1,cb2[4]); cb2[5]=fmaf(w1.y,p1,cb2[5]);
        cb2[6]=fmaf(w1.z,p1,cb2[6]); cb2[7]=fmaf(w1.w,p1,cb2[7]);
      }
      if (s < NS){
        float p0 = ps[s];
        const float4 v0 = *reinterpret_cast<const float4*>(vbase + (size_t)s*NKV);
        const float4 v1 = *reinterpret_cast<const float4*>(vbase + (size_t)s*NKV + 4);
        ca[0]=fmaf(v0.x,p0,ca[0]); ca[1]=fmaf(v0.y,p0,ca[1]);
        ca[2]=fmaf(v0.z,p0,ca[2]); ca[3]=fmaf(v0.w,p0,ca[3]);
        ca[4]=fmaf(v1.x,p0,ca[4]); ca[5]=fmaf(v1.y,p0,ca[5]);
        ca[6]=fmaf(v1.z,p0,ca[6]); ca[7]=fmaf(v1.w,p0,ca[7]);
      }
    }
    #pragma unroll
    for (int u=0;u<8;++u){
      float v = ca[u] + cb2[u];
      v += __shfl_xor(v, 32);
      if (lane < 32) ctxpart[wave][kc+u] = v;
    }
  }
  __syncthreads();
  if (tid < NKV){
    float ctxv = 0.f;
    #pragma unroll
    for (int w=0; w<8; ++w) ctxv += ctxpart[w][tid];
    ctxv *= invS;
    ctxs[tid] = ctxv;
    X1next[(size_t)b*NK + NE + tid] = ctxv;
  }
  __syncthreads();

  // pred[v] = bc[v] + sum_k [ctx||q][k] * Wc[v][k]  (16 parts x 32 k)
  {
    int vIdx = tid >> 4, part = tid & 15;
    if (vIdx < NV){
      float a = 0.f;
      int kb0 = part*32;
      for (int k=kb0; k<kb0+32; ++k){
        float xv = (k < NKV) ? ctxs[k] : qs[k-NKV];
        a = fmaf(xv, ldDual(Wc, (size_t)vIdx*(2*NKV) + k, bfm), a);
      }
      psum[vIdx][part] = a;
    }
  }
  __syncthreads();
  if (tid < NV){
    float a = ldDual(bc, tid, bfm);
    #pragma unroll
    for (int p=0;p<16;++p) a += psum[tid][p];
    size_t oi = (size_t)b*(NT*NV) + (size_t)t*NV + tid;
    if (bfm) ((bf*)outp)[oi] = __float2bfloat16(a);
    else     ((float*)outp)[oi] = a;
  }

  // stage next step's embedding row into X1next[:, 0:NE)
  if (t + 1 < NT && tid < NE){
    int yv = y[(size_t)(t+1)*NB + b];
    X1next[(size_t)b*NK + tid] = ldDual(emb, (size_t)yv*NE + tid, bfm);
  }
}

extern "C" void kernel_launch(void* const* d_in, const int* in_sizes, int n_in,
                              void* d_out, int out_size, void* d_ws, size_t ws_size,
                              hipStream_t stream)
{
  const void* enc_key = d_in[0];
  const void* value   = d_in[1];
  const int*  y       = (const int*)d_in[2];
  // d_in[3] = encoder_len, unused (reference discards the mask)
  const void* emb     = d_in[4];
  const void* W_ih1   = d_in[5];
  const void* b_ih1   = d_in[6];
  const void* W_hh1   = d_in[7];
  const void* b_hh1   = d_in[8];
  const void* W_ih2   = d_in[9];
  const void* b_ih2   = d_in[10];
  const void* W_hh2   = d_in[11];
  const void* b_hh2   = d_in[12];
  const void* Wq      = d_in[13];
  const void* bq      = d_in[14];
  const void* Wc      = d_in[15];
  const void* bc      = d_in[16];

  char* base = (char*)d_ws; size_t off = 0;
  auto alloc = [&](size_t bytes)->char*{
    char* p = base + off; off += (bytes + 255) & ~(size_t)255; return p;
  };
  float* Wtp1 = (float*)alloc((size_t)NK*NG*4);   // 8 MB
  float* Wtp2 = (float*)alloc((size_t)NK*NG*4);   // 8 MB
  float* bsum1 = (float*)alloc((size_t)NG*4);
  float* bsum2 = (float*)alloc((size_t)NG*4);
  float* X1[2] = {(float*)alloc((size_t)NB*NK*4), (float*)alloc((size_t)NB*NK*4)};
  float* X2[2] = {(float*)alloc((size_t)NB*NK*4), (float*)alloc((size_t)NB*NK*4)};
  float* c1 = (float*)alloc((size_t)NB*NH*4);
  float* c2 = (float*)alloc((size_t)NB*NH*4);
  unsigned* flag = (unsigned*)alloc(256);
  (void)ws_size;

  k_probe<<<1, 256, 0, stream>>>((const unsigned*)enc_key, flag);
  k_wtp<<<(NK*NG)/256, 256, 0, stream>>>(W_ih1, W_hh1, Wtp1, flag);
  k_wtp<<<(NK*NG)/256, 256, 0, stream>>>(W_ih2, W_hh2, Wtp2, flag);
  k_biasp<<<(2*NG)/256, 256, 0, stream>>>(b_ih1, b_hh1, b_ih2, b_hh2, bsum1, bsum2, flag);
  k_init<<<NB, 256, 0, stream>>>(value, y, emb, X1[0], X2[0], c1, c2, flag);

  for (int t=0; t<NT; ++t){
    int cur = t & 1, nxt = cur ^ 1;
    // LSTM1: X1[cur] -> (c1, h1);  c1n -> X2[cur][:,0:512), h1n -> X1[nxt][:,512:1024)
    k_lstm<<<256, 512, 0, stream>>>(X1[cur], Wtp1, bsum1, c1,
                                    X2[cur], NK, 1, X1[nxt] + NH);
    // LSTM2: X2[cur] -> (c2, h2);  h2n -> X2[nxt][:,512:1024); attn reads c2
    k_lstm<<<256, 512, 0, stream>>>(X2[cur], Wtp2, bsum2, c2,
                                    nullptr, 0, 0, X2[nxt] + NH);
    // attention + pred + next-step staging (512 threads, 2-way ILP)
    k_attn<<<NB, 512, 0, stream>>>(c2, Wq, bq, enc_key, value, Wc, bc,
                                   y, emb, X1[nxt], d_out, flag, t);
  }
}

// Round 12
// 38531.961 us; speedup vs baseline: 1.4245x; 1.0624x over previous
//
#include <hip/hip_runtime.h>
#include <hip/hip_bf16.h>

#define NB 128   // batch
#define NS 1000  // encoder length
#define NSH 500  // per-half s rows
#define NT 256   // decode steps
#define NV 30    // vocab
#define NE 256   // embed dim
#define NKV 256  // key/value dim
#define NH 512   // hidden
#define NG 2048  // 4*NH
#define NK 1024  // GEMM K dim

typedef __hip_bfloat16 bf;
typedef unsigned short ushortT;

__device__ __forceinline__ float sigm(float x){ return 1.f/(1.f+__expf(-x)); }
__device__ __forceinline__ float tanh_fast(float x){ float e=__expf(2.f*x); return 1.f - 2.f/(e+1.f); }
__device__ __forceinline__ float bf2f(ushortT u){ return __uint_as_float(((unsigned)u)<<16); }
__device__ __forceinline__ void bf8_to_f(const ushortT* p, float* o){
  uint4 u = *reinterpret_cast<const uint4*>(p);
  o[0]=__uint_as_float(u.x<<16); o[1]=__uint_as_float(u.x&0xffff0000u);
  o[2]=__uint_as_float(u.y<<16); o[3]=__uint_as_float(u.y&0xffff0000u);
  o[4]=__uint_as_float(u.z<<16); o[5]=__uint_as_float(u.z&0xffff0000u);
  o[6]=__uint_as_float(u.w<<16); o[7]=__uint_as_float(u.w&0xffff0000u);
}
__device__ __forceinline__ float ldDual(const void* p, size_t i, bool bfm){
  return bfm ? bf2f(((const ushortT*)p)[i]) : ((const float*)p)[i];
}

// ---- dtype probe ----
__global__ void k_probe(const unsigned* __restrict__ x, unsigned* __restrict__ flag){
  __shared__ int cnt;
  if (threadIdx.x==0) cnt = 0;
  __syncthreads();
  int c = 0;
  #pragma unroll
  for (int i=0;i<4;++i){
    unsigned d = x[(size_t)threadIdx.x*4 + i];
    unsigned e = (d >> 7) & 0xffu;
    c += (e >= 119 && e <= 135) ? 1 : 0;
  }
  atomicAdd(&cnt, c);
  __syncthreads();
  if (threadIdx.x==0) *flag = (cnt >= 512) ? 1u : 0u;
}

// ---- prep: permuted transposed weights (fp32) ----
__global__ void k_wtp(const void* __restrict__ A, const void* __restrict__ Bm,
                      float* __restrict__ Wtp, const unsigned* __restrict__ flag){
  const bool bfm = (*flag != 0);
  int idx = blockIdx.x*256 + threadIdx.x;       // over NK*NG
  int k = idx >> 11, pc = idx & (NG-1);
  int j = pc >> 2, g = pc & 3;
  int col = g*NH + j;
  const void* p = (k < NH) ? A : Bm;
  Wtp[idx] = ldDual(p, (size_t)col*NH + (k & (NH-1)), bfm);
}

// ---- prep: permuted bias sums ----
__global__ void k_biasp(const void* bi1, const void* bh1, const void* bi2, const void* bh2,
                        float* __restrict__ bsum1, float* __restrict__ bsum2,
                        const unsigned* __restrict__ flag){
  const bool bfm = (*flag != 0);
  int idx = blockIdx.x*256 + threadIdx.x;       // over 2*NG
  int which = idx >= NG; int pc = idx & (NG-1);
  int j = pc >> 2, g = pc & 3;
  int col = g*NH + j;
  const void* a = which ? bi2 : bi1;
  const void* c = which ? bh2 : bh1;
  float v = ldDual(a, col, bfm) + ldDual(c, col, bfm);
  (which ? bsum2 : bsum1)[pc] = v;
}

// ---- init ----
__global__ void k_init(const void* __restrict__ value, const int* __restrict__ y,
                       const void* __restrict__ emb,
                       float* __restrict__ X1a, float* __restrict__ X2a,
                       float* __restrict__ c1, float* __restrict__ c2,
                       const unsigned* __restrict__ flag){
  const bool bfm = (*flag != 0);
  int b = blockIdx.x, tid = threadIdx.x;
  float acc = 0.f;
  if (bfm){
    const ushortT* vcol = (const ushortT*)value + (size_t)b*NS*NKV + tid;
    for (int s=0;s<NS;++s) acc += bf2f(vcol[(size_t)s*NKV]);
  } else {
    const float* vcol = (const float*)value + (size_t)b*NS*NKV + tid;
    for (int s=0;s<NS;++s) acc += vcol[(size_t)s*NKV];
  }
  X1a[(size_t)b*NK + NE + tid] = acc * (1.f/NS);
  int yv = y[b];
  X1a[(size_t)b*NK + tid] = ldDual(emb, (size_t)yv*NE + tid, bfm);
  X1a[(size_t)b*NK + 512 + tid] = 0.f; X1a[(size_t)b*NK + 768 + tid] = 0.f;
  X2a[(size_t)b*NK + 512 + tid] = 0.f; X2a[(size_t)b*NK + 768 + tid] = 0.f;
  c1[(size_t)b*NH + tid] = 0.f; c1[(size_t)b*NH + 256 + tid] = 0.f;
  c2[(size_t)b*NH + tid] = 0.f; c2[(size_t)b*NH + 256 + tid] = 0.f;
}

// ---- per-step LSTM (validated, unchanged) ----
__global__ __launch_bounds__(512) void k_lstm(
    const float* __restrict__ X, const float* __restrict__ Wtp,
    const float* __restrict__ bsump,
    float* __restrict__ cstate,
    float* __restrict__ outC, int outCstride, int hasC,
    float* __restrict__ outH)
{
  const int i = blockIdx.x;
  const int cb = ((i & 7) << 3) | ((i >> 3) & 7);
  const int rb = i >> 6;
  const int r0 = rb * 32;
  const int pc0 = cb * 32;
  const int tid = threadIdx.x;
  const int khalf = tid >> 8;
  const int t8 = tid & 255;
  const int rp = t8 >> 4;
  const int cp = t8 & 15;
  __shared__ float Xs[2][64][33];
  __shared__ float redbuf[256][4];
  __shared__ float gbuf[32][33];

  float a00=0.f, a01=0.f, a10=0.f, a11=0.f;
  const int kbase = khalf * 512;
  const int sr  = t8 >> 4;
  const int sk4 = (t8 & 15) * 4;

  for (int cch = 0; cch < 8; ++cch){
    __syncthreads();
    {
      const float4 v0 = *reinterpret_cast<const float4*>(
          X + (size_t)(r0+sr)*NK + kbase + cch*64 + sk4);
      const float4 v1 = *reinterpret_cast<const float4*>(
          X + (size_t)(r0+sr+16)*NK + kbase + cch*64 + sk4);
      Xs[khalf][sk4+0][sr]    = v0.x; Xs[khalf][sk4+1][sr]    = v0.y;
      Xs[khalf][sk4+2][sr]    = v0.z; Xs[khalf][sk4+3][sr]    = v0.w;
      Xs[khalf][sk4+0][sr+16] = v1.x; Xs[khalf][sk4+1][sr+16] = v1.y;
      Xs[khalf][sk4+2][sr+16] = v1.z; Xs[khalf][sk4+3][sr+16] = v1.w;
    }
    __syncthreads();
    const float* wp = Wtp + (size_t)(kbase + cch*64)*NG + pc0 + cp*2;
    #pragma unroll 8
    for (int kk=0; kk<64; ++kk){
      const float2 w = *reinterpret_cast<const float2*>(wp + (size_t)kk*NG);
      const float2 x = *reinterpret_cast<const float2*>(&Xs[khalf][kk][rp*2]);
      a00 = fmaf(x.x, w.x, a00); a01 = fmaf(x.x, w.y, a01);
      a10 = fmaf(x.y, w.x, a10); a11 = fmaf(x.y, w.y, a11);
    }
  }
  if (khalf == 1){
    redbuf[t8][0]=a00; redbuf[t8][1]=a01; redbuf[t8][2]=a10; redbuf[t8][3]=a11;
  }
  __syncthreads();
  if (khalf == 0){
    a00 += redbuf[t8][0]; a01 += redbuf[t8][1];
    a10 += redbuf[t8][2]; a11 += redbuf[t8][3];
    gbuf[rp*2+0][cp*2+0]=a00; gbuf[rp*2+0][cp*2+1]=a01;
    gbuf[rp*2+1][cp*2+0]=a10; gbuf[rp*2+1][cp*2+1]=a11;
  }
  __syncthreads();
  if (tid < 256){
    const int er = tid >> 3;
    const int jj = tid & 7;
    const int r = r0 + er;
    const int jg = cb*8 + jj;
    const int pb = pc0 + jj*4;
    float iv = gbuf[er][jj*4+0] + bsump[pb+0];
    float fv = gbuf[er][jj*4+1] + bsump[pb+1];
    float gv = gbuf[er][jj*4+2] + bsump[pb+2];
    float ov = gbuf[er][jj*4+3] + bsump[pb+3];
    float cold = cstate[(size_t)r*NH + jg];
    float cn = sigm(fv)*cold + sigm(iv)*tanh_fast(gv);
    float hn = sigm(ov)*tanh_fast(cn);
    cstate[(size_t)r*NH + jg] = cn;
    if (hasC) outC[(size_t)r*outCstride + jg] = cn;
    outH[(size_t)r*NK + jg] = hn;
  }
}

// ---- attention part: 256 blocks (2 per b), 512 thr. q + energy(500) + local
//      softmax stats + unnormalized partial ctx. ----
__global__ __launch_bounds__(512) void k_attn_part(
    const float* __restrict__ c2, const void* __restrict__ Wq, const void* __restrict__ bq,
    const void* __restrict__ key, const void* __restrict__ val,
    float* __restrict__ qbuf, float* __restrict__ pctx, float* __restrict__ pstat,
    float* __restrict__ psbuf,
    const unsigned* __restrict__ flag)
{
  const bool bfm = (*flag != 0);
  const int b = blockIdx.x >> 1, half = blockIdx.x & 1;
  const int sbase = half * NSH;
  const int tid = threadIdx.x, lane = tid & 63, wave = tid >> 6;
  __shared__ float c2s[NH];
  __shared__ float qs[NKV];
  __shared__ float ps[512];
  __shared__ float red[16];
  __shared__ float ctxpart[8][NKV];

  c2s[tid] = c2[(size_t)b*NH + tid];
  __syncthreads();

  // q (duplicated across halves; half 0 publishes to qbuf)
  if (tid < NKV){
    float qacc = ldDual(bq, tid, bfm);
    if (bfm){
      const ushortT* wrow = (const ushortT*)Wq + (size_t)tid*NH;
      #pragma unroll 4
      for (int j=0;j<NH;j+=8){
        float wv[8]; bf8_to_f(wrow + j, wv);
        #pragma unroll
        for (int u=0;u<8;++u) qacc = fmaf(wv[u], c2s[j+u], qacc);
      }
    } else {
      const float4* wrow = reinterpret_cast<const float4*>((const float*)Wq + (size_t)tid*NH);
      #pragma unroll 4
      for (int j4=0; j4<NH/4; ++j4){
        float4 w = wrow[j4]; int j = j4*4;
        qacc = fmaf(w.x, c2s[j+0], qacc); qacc = fmaf(w.y, c2s[j+1], qacc);
        qacc = fmaf(w.z, c2s[j+2], qacc); qacc = fmaf(w.w, c2s[j+3], qacc);
      }
    }
    qs[tid] = qacc;
    if (half == 0) qbuf[(size_t)b*NKV + tid] = qacc;
  }
  __syncthreads();

  // energy for local rows [0,500): 16 lanes per s, 2 streams per lane-group
  const int k0 = (lane & 15)*16;
  float qreg[16];
  #pragma unroll
  for (int u=0;u<16;++u) qreg[u] = qs[k0+u];
  const float rscale = 0.031622776601683794f; // 1/sqrt(1000)
  for (int i0 = wave*8; i0 < NSH; i0 += 64){
    int sA = i0 + (lane >> 4);
    int sB = sA + 4;
    float aA = 0.f, aB = 0.f;
    if (bfm){
      if (sA < NSH){
        const ushortT* kp = (const ushortT*)key + ((size_t)b*NS + sbase + sA)*NKV + k0;
        float xv[8];
        bf8_to_f(kp, xv);
        #pragma unroll
        for (int u=0;u<8;++u) aA = fmaf(xv[u], qreg[u], aA);
        bf8_to_f(kp + 8, xv);
        #pragma unroll
        for (int u=0;u<8;++u) aA = fmaf(xv[u], qreg[8+u], aA);
      }
      if (sB < NSH){
        const ushortT* kp = (const ushortT*)key + ((size_t)b*NS + sbase + sB)*NKV + k0;
        float xv[8];
        bf8_to_f(kp, xv);
        #pragma unroll
        for (int u=0;u<8;++u) aB = fmaf(xv[u], qreg[u], aB);
        bf8_to_f(kp + 8, xv);
        #pragma unroll
        for (int u=0;u<8;++u) aB = fmaf(xv[u], qreg[8+u], aB);
      }
    } else {
      const float* kA = (const float*)key + ((size_t)b*NS + sbase + sA)*NKV + k0;
      const float* kB = (const float*)key + ((size_t)b*NS + sbase + sB)*NKV + k0;
      float4 a0,a1,a2,a3, b0,b1,b2,b3;
      bool gA = (sA < NSH), gB = (sB < NSH);
      if (gA){
        a0 = *reinterpret_cast<const float4*>(kA);
        a1 = *reinterpret_cast<const float4*>(kA+4);
        a2 = *reinterpret_cast<const float4*>(kA+8);
        a3 = *reinterpret_cast<const float4*>(kA+12);
      }
      if (gB){
        b0 = *reinterpret_cast<const float4*>(kB);
        b1 = *reinterpret_cast<const float4*>(kB+4);
        b2 = *reinterpret_cast<const float4*>(kB+8);
        b3 = *reinterpret_cast<const float4*>(kB+12);
      }
      if (gA){
        aA = fmaf(a0.x,qreg[0],aA); aA = fmaf(a0.y,qreg[1],aA);
        aA = fmaf(a0.z,qreg[2],aA); aA = fmaf(a0.w,qreg[3],aA);
        aA = fmaf(a1.x,qreg[4],aA); aA = fmaf(a1.y,qreg[5],aA);
        aA = fmaf(a1.z,qreg[6],aA); aA = fmaf(a1.w,qreg[7],aA);
        aA = fmaf(a2.x,qreg[8],aA); aA = fmaf(a2.y,qreg[9],aA);
        aA = fmaf(a2.z,qreg[10],aA); aA = fmaf(a2.w,qreg[11],aA);
        aA = fmaf(a3.x,qreg[12],aA); aA = fmaf(a3.y,qreg[13],aA);
        aA = fmaf(a3.z,qreg[14],aA); aA = fmaf(a3.w,qreg[15],aA);
      }
      if (gB){
        aB = fmaf(b0.x,qreg[0],aB); aB = fmaf(b0.y,qreg[1],aB);
        aB = fmaf(b0.z,qreg[2],aB); aB = fmaf(b0.w,qreg[3],aB);
        aB = fmaf(b1.x,qreg[4],aB); aB = fmaf(b1.y,qreg[5],aB);
        aB = fmaf(b1.z,qreg[6],aB); aB = fmaf(b1.w,qreg[7],aB);
        aB = fmaf(b2.x,qreg[8],aB); aB = fmaf(b2.y,qreg[9],aB);
        aB = fmaf(b2.z,qreg[10],aB); aB = fmaf(b2.w,qreg[11],aB);
        aB = fmaf(b3.x,qreg[12],aB); aB = fmaf(b3.y,qreg[13],aB);
        aB = fmaf(b3.z,qreg[14],aB); aB = fmaf(b3.w,qreg[15],aB);
      }
    }
    aA += __shfl_xor(aA,1); aA += __shfl_xor(aA,2);
    aA += __shfl_xor(aA,4); aA += __shfl_xor(aA,8);
    aB += __shfl_xor(aB,1); aB += __shfl_xor(aB,2);
    aB += __shfl_xor(aB,4); aB += __shfl_xor(aB,8);
    if ((lane & 15) == 0){
      if (sA < NSH) ps[sA] = (aA + 1e-9f)*rscale;
      if (sB < NSH) ps[sB] = (aB + 1e-9f)*rscale;
    }
  }
  __syncthreads();

  // local softmax stats over ps[0..500)
  float m = -1e30f;
  if (tid < NSH) m = ps[tid];
  #pragma unroll
  for (int d=1; d<64; d<<=1) m = fmaxf(m, __shfl_xor(m, d));
  if (lane == 0) red[wave] = m;
  __syncthreads();
  m = red[0];
  #pragma unroll
  for (int w=1; w<8; ++w) m = fmaxf(m, red[w]);
  float sum = 0.f;
  if (tid < NSH){ float p = __expf(ps[tid]-m); ps[tid] = p; sum = p; }
  #pragma unroll
  for (int d=1; d<64; d<<=1) sum += __shfl_xor(sum, d);
  if (lane == 0) red[8+wave] = sum;
  __syncthreads();
  sum = red[8];
  #pragma unroll
  for (int w=1; w<8; ++w) sum += red[8+w];
  if (tid == 0){
    pstat[((size_t)b*2 + half)*2 + 0] = m;
    pstat[((size_t)b*2 + half)*2 + 1] = sum;
  }
  if (b == 0 && tid < NSH) psbuf[sbase + tid] = ps[tid];

  // partial ctx (unnormalized): 16 s-streams x (32 lanes x 8 cols), 2-way unroll
  {
    float ca[8] = {0.f,0.f,0.f,0.f,0.f,0.f,0.f,0.f};
    float cb2[8] = {0.f,0.f,0.f,0.f,0.f,0.f,0.f,0.f};
    const int sset = lane >> 5;
    const int kc = (lane & 31) * 8;
    const int sst = wave*2 + sset;
    int s = sst;
    if (bfm){
      const ushortT* vbase = (const ushortT*)val + ((size_t)b*NS + sbase)*NKV + kc;
      for (; s + 16 < NSH; s += 32){
        float p0 = ps[s], p1 = ps[s+16];
        float xv[8];
        bf8_to_f(vbase + (size_t)s*NKV, xv);
        #pragma unroll
        for (int u=0;u<8;++u) ca[u] = fmaf(xv[u], p0, ca[u]);
        bf8_to_f(vbase + (size_t)(s+16)*NKV, xv);
        #pragma unroll
        for (int u=0;u<8;++u) cb2[u] = fmaf(xv[u], p1, cb2[u]);
      }
      if (s < NSH){
        float p0 = ps[s];
        float xv[8]; bf8_to_f(vbase + (size_t)s*NKV, xv);
        #pragma unroll
        for (int u=0;u<8;++u) ca[u] = fmaf(xv[u], p0, ca[u]);
      }
    } else {
      const float* vbase = (const float*)val + ((size_t)b*NS + sbase)*NKV + kc;
      for (; s + 16 < NSH; s += 32){
        float p0 = ps[s], p1 = ps[s+16];
        const float4 v0 = *reinterpret_cast<const float4*>(vbase + (size_t)s*NKV);
        const float4 v1 = *reinterpret_cast<const float4*>(vbase + (size_t)s*NKV + 4);
        const float4 w0 = *reinterpret_cast<const float4*>(vbase + (size_t)(s+16)*NKV);
        const float4 w1 = *reinterpret_cast<const float4*>(vbase + (size_t)(s+16)*NKV + 4);
        ca[0]=fmaf(v0.x,p0,ca[0]); ca[1]=fmaf(v0.y,p0,ca[1]);
        ca[2]=fmaf(v0.z,p0,ca[2]); ca[3]=fmaf(v0.w,p0,ca[3]);
        ca[4]=fmaf(v1.x,p0,ca[4]); ca[5]=fmaf(v1.y,p0,ca[5]);
        ca[6]=fmaf(v1.z,p0,ca[6]); ca[7]=fmaf(v1.w,p0,ca[7]);
        cb2[0]=fmaf(w0.x,p1,cb2[0]); cb2[1]=fmaf(w0.y,p1,cb2[1]);
        cb2[2]=fmaf(w0.z,p1,cb2[2]); cb2[3]=fmaf(w0.w,p1,cb2[3]);
        cb2[4]=fmaf(w1.x,p1,cb2[4]); cb2[5]=fmaf(w1.y,p1,cb2[5]);
        cb2[6]=fmaf(w1.z,p1,cb2[6]); cb2[7]=fmaf(w1.w,p1,cb2[7]);
      }
      if (s < NSH){
        float p0 = ps[s];
        const float4 v0 = *reinterpret_cast<const float4*>(vbase + (size_t)s*NKV);
        const float4 v1 = *reinterpret_cast<const float4*>(vbase + (size_t)s*NKV + 4);
        ca[0]=fmaf(v0.x,p0,ca[0]); ca[1]=fmaf(v0.y,p0,ca[1]);
        ca[2]=fmaf(v0.z,p0,ca[2]); ca[3]=fmaf(v0.w,p0,ca[3]);
        ca[4]=fmaf(v1.x,p0,ca[4]); ca[5]=fmaf(v1.y,p0,ca[5]);
        ca[6]=fmaf(v1.z,p0,ca[6]); ca[7]=fmaf(v1.w,p0,ca[7]);
      }
    }
    #pragma unroll
    for (int u=0;u<8;++u){
      float v = ca[u] + cb2[u];
      v += __shfl_xor(v, 32);
      if (lane < 32) ctxpart[wave][kc+u] = v;
    }
  }
  __syncthreads();
  if (tid < NKV){
    float ctxv = 0.f;
    #pragma unroll
    for (int w=0; w<8; ++w) ctxv += ctxpart[w][tid];
    pctx[((size_t)b*2 + half)*NKV + tid] = ctxv;
  }
}

// ---- attention combine: 128 blocks x 256 thr. Online-softmax merge + pred +
//      staging. ----
__global__ __launch_bounds__(256) void k_attn_comb(
    const float* __restrict__ qbuf, const float* __restrict__ pctx,
    const float* __restrict__ pstat, const float* __restrict__ psbuf,
    const void* __restrict__ Wc, const void* __restrict__ bc,
    const int* __restrict__ y, const void* __restrict__ emb,
    float* __restrict__ X1next, void* __restrict__ outp,
    const unsigned* __restrict__ flag, int t)
{
  const bool bfm = (*flag != 0);
  const int b = blockIdx.x, tid = threadIdx.x;
  __shared__ float qs[NKV];
  __shared__ float ctxs[NKV];
  __shared__ float psum[NV][9];

  const float mA = pstat[((size_t)b*2+0)*2+0], sA = pstat[((size_t)b*2+0)*2+1];
  const float mB = pstat[((size_t)b*2+1)*2+0], sB = pstat[((size_t)b*2+1)*2+1];
  const float m = fmaxf(mA, mB);
  const float wA = __expf(mA - m), wB = __expf(mB - m);
  const float invS = 1.f / (sA*wA + sB*wB);

  qs[tid] = qbuf[(size_t)b*NKV + tid];
  float ctxv = (pctx[((size_t)b*2+0)*NKV + tid]*wA +
                pctx[((size_t)b*2+1)*NKV + tid]*wB) * invS;
  ctxs[tid] = ctxv;
  X1next[(size_t)b*NK + NE + tid] = ctxv;

  const size_t ATTN_OFF = (size_t)NB*NT*NV;
  if (b == 0){
    for (int s=tid; s<NS; s+=256){
      float v = psbuf[s] * ((s < NSH) ? wA : wB) * invS;
      if (bfm) ((bf*)outp)[ATTN_OFF + (size_t)t*NS + s] = __float2bfloat16(v);
      else     ((float*)outp)[ATTN_OFF + (size_t)t*NS + s] = v;
    }
  }
  __syncthreads();

  // pred[v] = bc[v] + sum_k [ctx||q][k] * Wc[v][k]
  {
    int vIdx = tid >> 3, part = tid & 7;
    if (vIdx < NV){
      float a = 0.f;
      int kb0 = part*64;
      for (int k=kb0; k<kb0+64; ++k){
        float xv = (k < NKV) ? ctxs[k] : qs[k-NKV];
        a = fmaf(xv, ldDual(Wc, (size_t)vIdx*(2*NKV) + k, bfm), a);
      }
      psum[vIdx][part] = a;
    }
  }
  __syncthreads();
  if (tid < NV){
    float a = ldDual(bc, tid, bfm);
    #pragma unroll
    for (int p=0;p<8;++p) a += psum[tid][p];
    size_t oi = (size_t)b*(NT*NV) + (size_t)t*NV + tid;
    if (bfm) ((bf*)outp)[oi] = __float2bfloat16(a);
    else     ((float*)outp)[oi] = a;
  }

  // stage next step's embedding row
  if (t + 1 < NT){
    int yv = y[(size_t)(t+1)*NB + b];
    X1next[(size_t)b*NK + tid] = ldDual(emb, (size_t)yv*NE + tid, bfm);
  }
}

extern "C" void kernel_launch(void* const* d_in, const int* in_sizes, int n_in,
                              void* d_out, int out_size, void* d_ws, size_t ws_size,
                              hipStream_t stream)
{
  const void* enc_key = d_in[0];
  const void* value   = d_in[1];
  const int*  y       = (const int*)d_in[2];
  // d_in[3] = encoder_len, unused (reference discards the mask)
  const void* emb     = d_in[4];
  const void* W_ih1   = d_in[5];
  const void* b_ih1   = d_in[6];
  const void* W_hh1   = d_in[7];
  const void* b_hh1   = d_in[8];
  const void* W_ih2   = d_in[9];
  const void* b_ih2   = d_in[10];
  const void* W_hh2   = d_in[11];
  const void* b_hh2   = d_in[12];
  const void* Wq      = d_in[13];
  const void* bq      = d_in[14];
  const void* Wc      = d_in[15];
  const void* bc      = d_in[16];

  char* base = (char*)d_ws; size_t off = 0;
  auto alloc = [&](size_t bytes)->char*{
    char* p = base + off; off += (bytes + 255) & ~(size_t)255; return p;
  };
  float* Wtp1 = (float*)alloc((size_t)NK*NG*4);   // 8 MB
  float* Wtp2 = (float*)alloc((size_t)NK*NG*4);   // 8 MB
  float* bsum1 = (float*)alloc((size_t)NG*4);
  float* bsum2 = (float*)alloc((size_t)NG*4);
  float* X1[2] = {(float*)alloc((size_t)NB*NK*4), (float*)alloc((size_t)NB*NK*4)};
  float* X2[2] = {(float*)alloc((size_t)NB*NK*4), (float*)alloc((size_t)NB*NK*4)};
  float* c1 = (float*)alloc((size_t)NB*NH*4);
  float* c2 = (float*)alloc((size_t)NB*NH*4);
  float* qbuf  = (float*)alloc((size_t)NB*NKV*4);
  float* pctx  = (float*)alloc((size_t)NB*2*NKV*4);
  float* pstat = (float*)alloc((size_t)NB*2*2*4);
  float* psbuf = (float*)alloc((size_t)NS*4);
  unsigned* flag = (unsigned*)alloc(256);
  (void)ws_size;

  k_probe<<<1, 256, 0, stream>>>((const unsigned*)enc_key, flag);
  k_wtp<<<(NK*NG)/256, 256, 0, stream>>>(W_ih1, W_hh1, Wtp1, flag);
  k_wtp<<<(NK*NG)/256, 256, 0, stream>>>(W_ih2, W_hh2, Wtp2, flag);
  k_biasp<<<(2*NG)/256, 256, 0, stream>>>(b_ih1, b_hh1, b_ih2, b_hh2, bsum1, bsum2, flag);
  k_init<<<NB, 256, 0, stream>>>(value, y, emb, X1[0], X2[0], c1, c2, flag);

  for (int t=0; t<NT; ++t){
    int cur = t & 1, nxt = cur ^ 1;
    k_lstm<<<256, 512, 0, stream>>>(X1[cur], Wtp1, bsum1, c1,
                                    X2[cur], NK, 1, X1[nxt] + NH);
    k_lstm<<<256, 512, 0, stream>>>(X2[cur], Wtp2, bsum2, c2,
                                    nullptr, 0, 0, X2[nxt] + NH);
    k_attn_part<<<2*NB, 512, 0, stream>>>(c2, Wq, bq, enc_key, value,
                                          qbuf, pctx, pstat, psbuf, flag);
    k_attn_comb<<<NB, 256, 0, stream>>>(qbuf, pctx, pstat, psbuf, Wc, bc,
                                        y, emb, X1[nxt], d_out, flag, t);
  }
}